// Round 2
// baseline (98719.946 us; speedup 1.0000x reference)
//
#include <hip/hip_runtime.h>
#include <math.h>

// ---------------------------------------------------------------------------
// TimeSeriesTransformerDecoder — single cooperative mega-kernel.
//  * KV-cached incremental decoding (exact under causal mask).
//  * Cross-attn T=1 -> softmax==1 -> per-layer constant ca_add.
//  * All phases in one kernel; custom device-scope grid barrier (~723 barriers)
//    replaces ~754 serial kernel launches.
// ---------------------------------------------------------------------------

#define B    256
#define D    512
#define H    8
#define HD   64
#define L    4
#define FF   2048
#define P    24
#define NBLK 256
#define NTHR 512
#define CS   ((size_t)B * H * P * HD)   // per-layer KV-cache stride

struct MegaArgs {
  const float *context, *start_token, *ctx_W, *ctx_b, *ve_W, *ve_b;
  const float *sa_in_w, *sa_in_b, *sa_out_w, *sa_out_b;
  const float *ca_in_w, *ca_in_b, *ca_out_w, *ca_out_b;
  const float *lin1_w, *lin1_b, *lin2_w, *lin2_b;
  const float *ln1_w, *ln1_b, *ln2_w, *ln2_b, *ln3_w, *ln3_b;
  const float *o1_w, *o1_b, *o2_w, *o2_b;
  float *out;
  float *pe, *vals, *memory, *ca_add, *x, *qkv, *attn_o, *U, *hbuf, *part, *hh,
        *kcache, *vcache;
};

// ---- grid barrier state (device globals persist across graph replays;
//      epoch is monotonic, g_base carries it launch-to-launch: no resets,
//      identical work every call).
__device__ unsigned g_flags[NBLK];   // zero-init
__device__ unsigned g_epoch = 0;
__device__ unsigned g_base  = 0;

__device__ __forceinline__ void grid_bar(unsigned &bno)
{
  ++bno;
  __threadfence();            // make this thread's stores device-visible
  __syncthreads();
  if (threadIdx.x == 0)
    __hip_atomic_store(&g_flags[blockIdx.x], bno, __ATOMIC_RELEASE,
                       __HIP_MEMORY_SCOPE_AGENT);
  if (blockIdx.x == 0) {
    if (threadIdx.x < NBLK) {
      while (__hip_atomic_load(&g_flags[threadIdx.x], __ATOMIC_ACQUIRE,
                               __HIP_MEMORY_SCOPE_AGENT) < bno)
        __builtin_amdgcn_s_sleep(2);
    }
    __syncthreads();
    if (threadIdx.x == 0)
      __hip_atomic_store(&g_epoch, bno, __ATOMIC_RELEASE,
                         __HIP_MEMORY_SCOPE_AGENT);
  } else {
    if (threadIdx.x == 0) {
      while (__hip_atomic_load(&g_epoch, __ATOMIC_ACQUIRE,
                               __HIP_MEMORY_SCOPE_AGENT) < bno)
        __builtin_amdgcn_s_sleep(2);
    }
  }
  __syncthreads();
  __threadfence();            // invalidate stale cached lines before reads
}

__device__ __forceinline__ float gelu_f(float v)
{
  return 0.5f * v * (1.0f + erff(v * 0.70710678118654752f));
}

// ---------------------------------------------------------------------------
// 64x64 output tile GEMM over a 512-long K chunk. 512 threads, 2x4 micro-tile.
// C[m,n] = sum_k A[m,k0+k] * W[n,k0+k]  (+bias, + epilogue variant)
// LOADER: 0 = load A from memory; 1 = compute embedding on the fly
// EPI: 0=bias, 1=bias+gelu, 2=bias+qkv-store+kv-cache-scatter,
//      3=raw partial (no bias), 4=bias+residual(xres) -> C
// ---------------------------------------------------------------------------
template <int LOADER, int EPI>
__device__ void gemm64(float* sh, const float* A, int lda,
                       const float* W, int ldw, const float* bias,
                       float* C, int ldc, int m0, int n0, int k0,
                       const float* xres,
                       float* kcp, float* vcp, int t,
                       const float* valst, const float* veW, const float* veb,
                       const float* pet, float* xout)
{
  float* As = sh;             // [16][68]
  float* Ws = sh + 16 * 68;   // [16][68]
  const int tid = threadIdx.x;
  const int tm = tid >> 4;    // 0..31 -> rows tm*2, tm*2+1
  const int tn = tid & 15;    // 0..15 -> cols tn*4..+3
  float acc[2][4] = {};

  for (int kb = 0; kb < 512; kb += 16) {
#pragma unroll
    for (int i = 0; i < 2; i++) {
      const int idx = tid + i * 512;        // 0..1023
      const int r = idx >> 4;               // 0..63
      const int c = idx & 15;               // 0..15
      float av;
      if constexpr (LOADER == 1) {
        const int k = kb + c;
        av = valst[m0 + r] * veW[k] + veb[k] + pet[k];
        if (xout) xout[(m0 + r) * D + k] = av;
      } else {
        av = A[(size_t)(m0 + r) * lda + k0 + kb + c];
      }
      As[c * 68 + r] = av;
      Ws[c * 68 + r] = W[(size_t)(n0 + r) * ldw + k0 + kb + c];
    }
    __syncthreads();
#pragma unroll
    for (int kk = 0; kk < 16; kk++) {
      const float2 a2 = *(const float2*)(As + kk * 68 + tm * 2);
      const float4 w4 = *(const float4*)(Ws + kk * 68 + tn * 4);
      acc[0][0] = fmaf(a2.x, w4.x, acc[0][0]);
      acc[0][1] = fmaf(a2.x, w4.y, acc[0][1]);
      acc[0][2] = fmaf(a2.x, w4.z, acc[0][2]);
      acc[0][3] = fmaf(a2.x, w4.w, acc[0][3]);
      acc[1][0] = fmaf(a2.y, w4.x, acc[1][0]);
      acc[1][1] = fmaf(a2.y, w4.y, acc[1][1]);
      acc[1][2] = fmaf(a2.y, w4.z, acc[1][2]);
      acc[1][3] = fmaf(a2.y, w4.w, acc[1][3]);
    }
    __syncthreads();
  }

#pragma unroll
  for (int i = 0; i < 2; i++) {
    const int m = m0 + tm * 2 + i;
#pragma unroll
    for (int j = 0; j < 4; j++) {
      const int n = n0 + tn * 4 + j;
      float v = acc[i][j];
      if constexpr (EPI != 3) v += bias[n];
      if constexpr (EPI == 1) v = gelu_f(v);
      if constexpr (EPI == 4) v += xres[(size_t)m * D + n];
      C[(size_t)m * ldc + n] = v;
      if constexpr (EPI == 2) {
        if (n >= 2 * D) {
          const int f = n - 2 * D;
          vcp[((size_t)(m * H + (f >> 6)) * P + t) * HD + (f & 63)] = v;
        } else if (n >= D) {
          const int f = n - D;
          kcp[((size_t)(m * H + (f >> 6)) * P + t) * HD + (f & 63)] = v;
        }
      }
    }
  }
}

// block-wide sum over 512 threads (8 waves)
__device__ __forceinline__ float rsum512(float v, float* sbf)
{
#pragma unroll
  for (int o = 32; o; o >>= 1) v += __shfl_xor(v, o);
  const int wid = threadIdx.x >> 6;
  if ((threadIdx.x & 63) == 0) sbf[wid] = v;
  __syncthreads();
  float s = 0.f;
#pragma unroll
  for (int w = 0; w < 8; w++) s += sbf[w];
  __syncthreads();
  return s;
}

__global__ __launch_bounds__(NTHR) void mega(MegaArgs a)
{
  __shared__ float sh[2 * 16 * 68];
  __shared__ float sbf[8];
  const int blk = blockIdx.x;
  unsigned bno = __hip_atomic_load(&g_base, __ATOMIC_RELAXED,
                                   __HIP_MEMORY_SCOPE_AGENT);

  // ---- S1: memory = context @ ctx_W^T + b (32 jobs) | pe table | vals init
  if (blk < 32) {
    gemm64<0, 0>(sh, a.context, D, a.ctx_W, D, a.ctx_b, a.memory, D,
                 (blk & 3) * 64, (blk >> 2) * 64, 0,
                 nullptr, nullptr, nullptr, 0,
                 nullptr, nullptr, nullptr, nullptr, nullptr);
  } else if (blk < 56) {
    const int tt = blk - 32;
    const int dd = threadIdx.x;
    const float fr = expf((float)(dd & ~1) * (-9.210340371976184f / (float)D));
    const float ang = (float)tt * fr;
    a.pe[tt * D + dd] = (dd & 1) ? cosf(ang) : sinf(ang);
  } else if (blk == 56) {
    if (threadIdx.x < B) a.vals[threadIdx.x] = a.start_token[0];
  }
  grid_bar(bno);

  // ---- S2: part[l] = memory @ Wv_ca[l]^T + bv   (cross-attn V, T=1)
  if (blk < 128) {
    const int l = blk >> 5, tile = blk & 31;
    gemm64<0, 0>(sh, a.memory, D,
                 a.ca_in_w + (size_t)l * 3 * D * D + (size_t)2 * D * D, D,
                 a.ca_in_b + l * 3 * D + 2 * D,
                 a.part + (size_t)l * B * D, D,
                 (tile & 3) * 64, (tile >> 2) * 64, 0,
                 nullptr, nullptr, nullptr, 0,
                 nullptr, nullptr, nullptr, nullptr, nullptr);
  }
  grid_bar(bno);

  // ---- S3: ca_add[l] = part[l] @ Wo_ca[l]^T + bo
  if (blk < 128) {
    const int l = blk >> 5, tile = blk & 31;
    gemm64<0, 0>(sh, a.part + (size_t)l * B * D, D,
                 a.ca_out_w + (size_t)l * D * D, D, a.ca_out_b + l * D,
                 a.ca_add + (size_t)l * B * D, D,
                 (tile & 3) * 64, (tile >> 2) * 64, 0,
                 nullptr, nullptr, nullptr, 0,
                 nullptr, nullptr, nullptr, nullptr, nullptr);
  }
  grid_bar(bno);

  // ---- autoregressive decode --------------------------------------------
  for (int t = 0; t < P; t++) {
    for (int l = 0; l < L; l++) {
      float* kcp = a.kcache + (size_t)l * CS;
      float* vcp = a.vcache + (size_t)l * CS;

      // QKV projection (96 jobs); l==0 computes embedding inline and the
      // n0==0 blocks persist x for the residual path.
      if (blk < 96) {
        const int m0 = (blk & 3) * 64, n0 = (blk >> 2) * 64;
        if (l == 0)
          gemm64<1, 2>(sh, nullptr, 0, a.sa_in_w, D, a.sa_in_b, a.qkv, 3 * D,
                       m0, n0, 0, nullptr, kcp, vcp, t,
                       a.vals + (size_t)t * B, a.ve_W, a.ve_b, a.pe + t * D,
                       (n0 == 0) ? a.x : nullptr);
        else
          gemm64<0, 2>(sh, a.x, D, a.sa_in_w + (size_t)l * 3 * D * D, D,
                       a.sa_in_b + l * 3 * D, a.qkv, 3 * D, m0, n0, 0,
                       nullptr, kcp, vcp, t,
                       nullptr, nullptr, nullptr, nullptr, nullptr);
      }
      grid_bar(bno);

      // causal attention for position t: one wave per (b,h), 2048 units.
      {
        const int wid = threadIdx.x >> 6, lane = threadIdx.x & 63;
        const int u = blk * 8 + wid;
        const int b = u >> 3, h = u & 7;
        const float q = a.qkv[(size_t)b * 3 * D + h * HD + lane];
        const float* kb = kcp + (size_t)(b * H + h) * P * HD;
        const float* vb = vcp + (size_t)(b * H + h) * P * HD;
        float sc[P];
        const int nn = t + 1;
#pragma unroll
        for (int j = 0; j < P; j++)
          if (j < nn) {
            float p = q * kb[j * HD + lane];
#pragma unroll
            for (int o = 32; o; o >>= 1) p += __shfl_xor(p, o);
            sc[j] = p * 0.125f;   // 1/sqrt(64)
          }
        float mx = -1e30f;
#pragma unroll
        for (int j = 0; j < P; j++)
          if (j < nn) mx = fmaxf(mx, sc[j]);
        float s = 0.f;
#pragma unroll
        for (int j = 0; j < P; j++)
          if (j < nn) { sc[j] = expf(sc[j] - mx); s += sc[j]; }
        const float inv = 1.0f / s;
        float o = 0.f;
#pragma unroll
        for (int j = 0; j < P; j++)
          if (j < nn) o = fmaf(sc[j], vb[j * HD + lane], o);
        a.attn_o[(size_t)b * D + h * HD + lane] = o * inv;
      }
      grid_bar(bno);

      // output projection + residual:  U = x + attn_o @ Wo^T + bo  (32 jobs)
      if (blk < 32)
        gemm64<0, 4>(sh, a.attn_o, D, a.sa_out_w + (size_t)l * D * D, D,
                     a.sa_out_b + l * D, a.U, D,
                     (blk & 3) * 64, (blk >> 2) * 64, 0,
                     a.x, nullptr, nullptr, 0,
                     nullptr, nullptr, nullptr, nullptr, nullptr);
      grid_bar(bno);

      // x = LN2( LN1(U) + ca_add[l] )   — one block per row
      {
        const int b = blk, dd = threadIdx.x;
        const float u = a.U[(size_t)b * D + dd];
        const float m1 = rsum512(u, sbf) * (1.0f / D);
        const float d1 = u - m1;
        const float v1 = rsum512(d1 * d1, sbf) * (1.0f / D);
        const float z = d1 * rsqrtf(v1 + 1e-5f) * a.ln1_w[l * D + dd]
                        + a.ln1_b[l * D + dd];
        const float r2 = z + a.ca_add[(size_t)l * B * D + b * D + dd];
        const float m2 = rsum512(r2, sbf) * (1.0f / D);
        const float d2 = r2 - m2;
        const float v2 = rsum512(d2 * d2, sbf) * (1.0f / D);
        a.x[(size_t)b * D + dd] = d2 * rsqrtf(v2 + 1e-5f)
                                  * a.ln2_w[l * D + dd] + a.ln2_b[l * D + dd];
      }
      grid_bar(bno);

      // FFN1: hbuf = gelu(x @ W1^T + b1)   (128 jobs)
      if (blk < 128)
        gemm64<0, 1>(sh, a.x, D, a.lin1_w + (size_t)l * FF * D, D,
                     a.lin1_b + l * FF, a.hbuf, FF,
                     (blk & 3) * 64, (blk >> 2) * 64, 0,
                     nullptr, nullptr, nullptr, 0,
                     nullptr, nullptr, nullptr, nullptr, nullptr);
      grid_bar(bno);

      // FFN2 split-K: part[kc] = hbuf[:,kc*512:+512] @ W2[:,same]^T  (128 jobs)
      if (blk < 128) {
        const int kc4 = blk >> 5, tile = blk & 31;
        gemm64<0, 3>(sh, a.hbuf, FF, a.lin2_w + (size_t)l * D * FF, FF,
                     nullptr, a.part + (size_t)kc4 * B * D, D,
                     (tile & 3) * 64, (tile >> 2) * 64, kc4 * 512,
                     nullptr, nullptr, nullptr, 0,
                     nullptr, nullptr, nullptr, nullptr, nullptr);
      }
      grid_bar(bno);

      // x = LN3( x + sum(part) + b2 )
      {
        const int b = blk, dd = threadIdx.x;
        const size_t o = (size_t)b * D + dd;
        const float s0 = a.x[o] + a.part[o] + a.part[(size_t)B * D + o]
                       + a.part[(size_t)2 * B * D + o]
                       + a.part[(size_t)3 * B * D + o] + a.lin2_b[l * D + dd];
        const float m1 = rsum512(s0, sbf) * (1.0f / D);
        const float d1 = s0 - m1;
        const float v1 = rsum512(d1 * d1, sbf) * (1.0f / D);
        a.x[o] = d1 * rsqrtf(v1 + 1e-5f) * a.ln3_w[l * D + dd]
                 + a.ln3_b[l * D + dd];
      }
      grid_bar(bno);
    }

    // head stage 1: hh = gelu(x @ o1_w^T + o1_b)   (16 jobs)
    if (blk < 16)
      gemm64<0, 1>(sh, a.x, D, a.o1_w, D, a.o1_b, a.hh, 256,
                   (blk & 3) * 64, (blk >> 2) * 64, 0,
                   nullptr, nullptr, nullptr, 0,
                   nullptr, nullptr, nullptr, nullptr, nullptr);
    grid_bar(bno);

    // head stage 2: nv = hh @ o2_w^T + o2_b ; store out + vals[t+1]
    if (blk < 32) {
      const int wid = threadIdx.x >> 6, lane = threadIdx.x & 63;
      const int r = blk * 8 + wid;
      float p = 0.f;
#pragma unroll
      for (int i = 0; i < 4; i++)
        p = fmaf(a.hh[(size_t)r * 256 + lane + i * 64], a.o2_w[lane + i * 64], p);
#pragma unroll
      for (int o = 32; o; o >>= 1) p += __shfl_xor(p, o);
      if (lane == 0) {
        const float v = p + a.o2_b[0];
        a.vals[(size_t)(t + 1) * B + r] = v;
        a.out[(size_t)r * P + t] = v;
      }
    }
    grid_bar(bno);
  }

  if (blk == 0 && threadIdx.x == 0)
    __hip_atomic_store(&g_base, bno, __ATOMIC_RELAXED,
                       __HIP_MEMORY_SCOPE_AGENT);
}

// ---------------------------------------------------------------------------
extern "C" void kernel_launch(void* const* d_in, const int* in_sizes, int n_in,
                              void* d_out, int out_size, void* d_ws,
                              size_t ws_size, hipStream_t stream)
{
  (void)in_sizes; (void)n_in; (void)out_size; (void)ws_size;
  MegaArgs h;
  h.context     = (const float*)d_in[0];
  h.start_token = (const float*)d_in[1];
  h.ctx_W  = (const float*)d_in[2];
  h.ctx_b  = (const float*)d_in[3];
  h.ve_W   = (const float*)d_in[4];
  h.ve_b   = (const float*)d_in[5];
  h.sa_in_w  = (const float*)d_in[6];
  h.sa_in_b  = (const float*)d_in[7];
  h.sa_out_w = (const float*)d_in[8];
  h.sa_out_b = (const float*)d_in[9];
  h.ca_in_w  = (const float*)d_in[10];
  h.ca_in_b  = (const float*)d_in[11];
  h.ca_out_w = (const float*)d_in[12];
  h.ca_out_b = (const float*)d_in[13];
  h.lin1_w = (const float*)d_in[14];
  h.lin1_b = (const float*)d_in[15];
  h.lin2_w = (const float*)d_in[16];
  h.lin2_b = (const float*)d_in[17];
  h.ln1_w = (const float*)d_in[18];
  h.ln1_b = (const float*)d_in[19];
  h.ln2_w = (const float*)d_in[20];
  h.ln2_b = (const float*)d_in[21];
  h.ln3_w = (const float*)d_in[22];
  h.ln3_b = (const float*)d_in[23];
  h.o1_w = (const float*)d_in[24];
  h.o1_b = (const float*)d_in[25];
  h.o2_w = (const float*)d_in[26];
  h.o2_b = (const float*)d_in[27];
  h.out = (float*)d_out;

  float* ws = (float*)d_ws;
  size_t off = 0;
  h.pe      = ws + off; off += (size_t)P * D;
  h.vals    = ws + off; off += (size_t)(P + 1) * B;
  h.memory  = ws + off; off += (size_t)B * D;
  h.ca_add  = ws + off; off += (size_t)L * B * D;
  h.x       = ws + off; off += (size_t)B * D;
  h.qkv     = ws + off; off += (size_t)B * 3 * D;
  h.attn_o  = ws + off; off += (size_t)B * D;
  h.U       = ws + off; off += (size_t)B * D;
  h.hbuf    = ws + off; off += (size_t)B * FF;
  h.part    = ws + off; off += (size_t)4 * B * D;   // aliases setup vtmp
  h.hh      = ws + off; off += (size_t)B * 256;
  h.kcache  = ws + off; off += (size_t)L * CS;
  h.vcache  = ws + off; off += (size_t)L * CS;

  void* kargs[] = { &h };
  hipLaunchCooperativeKernel(mega, dim3(NBLK), dim3(NTHR), kargs, 0, stream);
}

// Round 3
// 23981.723 us; speedup vs baseline: 4.1165x; 4.1165x over previous
//
#include <hip/hip_runtime.h>
#include <math.h>

// ---------------------------------------------------------------------------
// TimeSeriesTransformerDecoder — single cooperative mega-kernel, v2.
//  * KV-cached incremental decoding (exact under causal mask).
//  * Cross-attn T=1 -> softmax==1 -> per-layer constant ca_add.
//  * v2: low-contention grid barrier (single counter, leader-only arrival,
//    RELAXED polling + s_sleep backoff, leader-only fences). v1's barrier
//    spun with per-poll ACQUIRE loads from 256+ threads -> ~170us/barrier.
// ---------------------------------------------------------------------------

#define B    256
#define D    512
#define H    8
#define HD   64
#define L    4
#define FF   2048
#define P    24
#define NBLK 256
#define NTHR 512
#define CS   ((size_t)B * H * P * HD)   // per-layer KV-cache stride

struct MegaArgs {
  const float *context, *start_token, *ctx_W, *ctx_b, *ve_W, *ve_b;
  const float *sa_in_w, *sa_in_b, *sa_out_w, *sa_out_b;
  const float *ca_in_w, *ca_in_b, *ca_out_w, *ca_out_b;
  const float *lin1_w, *lin1_b, *lin2_w, *lin2_b;
  const float *ln1_w, *ln1_b, *ln2_w, *ln2_b, *ln3_w, *ln3_b;
  const float *o1_w, *o1_b, *o2_w, *o2_b;
  float *out;
  float *pe, *vals, *memory, *ca_add, *x, *qkv, *attn_o, *U, *hbuf, *part, *hh,
        *kcache, *vcache;
};

// ---- grid barrier state. Monotonic across graph replays (no resets, no
//      call-count-dependent behavior). Each word on its own cache line.
__device__ __align__(128) unsigned g_count = 0;  // arrivals, monotonic
__device__ __align__(128) unsigned g_gen   = 0;  // published generation
__device__ __align__(128) unsigned g_base  = 0;  // epoch carried across launches

__device__ __forceinline__ void grid_bar(unsigned &bno)
{
  ++bno;
  __syncthreads();   // drains all waves' stores (waitcnt vmcnt(0) before s_barrier)
  if (threadIdx.x == 0) {
    __threadfence();  // agent fence: XCD L2 writeback -> coherence point
    const unsigned old = __hip_atomic_fetch_add(&g_count, 1u, __ATOMIC_RELAXED,
                                                __HIP_MEMORY_SCOPE_AGENT);
    if (old == bno * NBLK - 1u) {
      __hip_atomic_store(&g_gen, bno, __ATOMIC_RELEASE,
                         __HIP_MEMORY_SCOPE_AGENT);
    } else {
      while (__hip_atomic_load(&g_gen, __ATOMIC_RELAXED,
                               __HIP_MEMORY_SCOPE_AGENT) < bno)
        __builtin_amdgcn_s_sleep(8);
    }
    __threadfence();  // acquire side: invalidate stale cached lines
  }
  __syncthreads();    // releases the block after leader's fence
}

__device__ __forceinline__ float gelu_f(float v)
{
  return 0.5f * v * (1.0f + erff(v * 0.70710678118654752f));
}

// ---------------------------------------------------------------------------
// 64x64 output tile GEMM over a 512-long K chunk. 512 threads, 2x4 micro-tile.
// C[m,n] = sum_k A[m,k0+k] * W[n,k0+k]  (+bias, + epilogue variant)
// LOADER: 0 = load A from memory; 1 = compute embedding on the fly
// EPI: 0=bias, 1=bias+gelu, 2=bias+qkv-store+kv-cache-scatter,
//      3=raw partial (no bias), 4=bias+residual(xres) -> C
// ---------------------------------------------------------------------------
template <int LOADER, int EPI>
__device__ void gemm64(float* sh, const float* A, int lda,
                       const float* W, int ldw, const float* bias,
                       float* C, int ldc, int m0, int n0, int k0,
                       const float* xres,
                       float* kcp, float* vcp, int t,
                       const float* valst, const float* veW, const float* veb,
                       const float* pet, float* xout)
{
  float* As = sh;             // [16][68]
  float* Ws = sh + 16 * 68;   // [16][68]
  const int tid = threadIdx.x;
  const int tm = tid >> 4;    // 0..31 -> rows tm*2, tm*2+1
  const int tn = tid & 15;    // 0..15 -> cols tn*4..+3
  float acc[2][4] = {};

  for (int kb = 0; kb < 512; kb += 16) {
#pragma unroll
    for (int i = 0; i < 2; i++) {
      const int idx = tid + i * 512;        // 0..1023
      const int r = idx >> 4;               // 0..63
      const int c = idx & 15;               // 0..15
      float av;
      if constexpr (LOADER == 1) {
        const int k = kb + c;
        av = valst[m0 + r] * veW[k] + veb[k] + pet[k];
        if (xout) xout[(m0 + r) * D + k] = av;
      } else {
        av = A[(size_t)(m0 + r) * lda + k0 + kb + c];
      }
      As[c * 68 + r] = av;
      Ws[c * 68 + r] = W[(size_t)(n0 + r) * ldw + k0 + kb + c];
    }
    __syncthreads();
#pragma unroll
    for (int kk = 0; kk < 16; kk++) {
      const float2 a2 = *(const float2*)(As + kk * 68 + tm * 2);
      const float4 w4 = *(const float4*)(Ws + kk * 68 + tn * 4);
      acc[0][0] = fmaf(a2.x, w4.x, acc[0][0]);
      acc[0][1] = fmaf(a2.x, w4.y, acc[0][1]);
      acc[0][2] = fmaf(a2.x, w4.z, acc[0][2]);
      acc[0][3] = fmaf(a2.x, w4.w, acc[0][3]);
      acc[1][0] = fmaf(a2.y, w4.x, acc[1][0]);
      acc[1][1] = fmaf(a2.y, w4.y, acc[1][1]);
      acc[1][2] = fmaf(a2.y, w4.z, acc[1][2]);
      acc[1][3] = fmaf(a2.y, w4.w, acc[1][3]);
    }
    __syncthreads();
  }

#pragma unroll
  for (int i = 0; i < 2; i++) {
    const int m = m0 + tm * 2 + i;
#pragma unroll
    for (int j = 0; j < 4; j++) {
      const int n = n0 + tn * 4 + j;
      float v = acc[i][j];
      if constexpr (EPI != 3) v += bias[n];
      if constexpr (EPI == 1) v = gelu_f(v);
      if constexpr (EPI == 4) v += xres[(size_t)m * D + n];
      C[(size_t)m * ldc + n] = v;
      if constexpr (EPI == 2) {
        if (n >= 2 * D) {
          const int f = n - 2 * D;
          vcp[((size_t)(m * H + (f >> 6)) * P + t) * HD + (f & 63)] = v;
        } else if (n >= D) {
          const int f = n - D;
          kcp[((size_t)(m * H + (f >> 6)) * P + t) * HD + (f & 63)] = v;
        }
      }
    }
  }
}

// block-wide sum over 512 threads (8 waves)
__device__ __forceinline__ float rsum512(float v, float* sbf)
{
#pragma unroll
  for (int o = 32; o; o >>= 1) v += __shfl_xor(v, o);
  const int wid = threadIdx.x >> 6;
  if ((threadIdx.x & 63) == 0) sbf[wid] = v;
  __syncthreads();
  float s = 0.f;
#pragma unroll
  for (int w = 0; w < 8; w++) s += sbf[w];
  __syncthreads();
  return s;
}

__global__ __launch_bounds__(NTHR) void mega(MegaArgs a)
{
  __shared__ float sh[2 * 16 * 68];
  __shared__ float sbf[8];
  const int blk = blockIdx.x;
  unsigned bno = __hip_atomic_load(&g_base, __ATOMIC_RELAXED,
                                   __HIP_MEMORY_SCOPE_AGENT);

  // ---- S1: memory = context @ ctx_W^T + b (32 jobs) | pe table | vals init
  if (blk < 32) {
    gemm64<0, 0>(sh, a.context, D, a.ctx_W, D, a.ctx_b, a.memory, D,
                 (blk & 3) * 64, (blk >> 2) * 64, 0,
                 nullptr, nullptr, nullptr, 0,
                 nullptr, nullptr, nullptr, nullptr, nullptr);
  } else if (blk < 56) {
    const int tt = blk - 32;
    const int dd = threadIdx.x;
    const float fr = expf((float)(dd & ~1) * (-9.210340371976184f / (float)D));
    const float ang = (float)tt * fr;
    a.pe[tt * D + dd] = (dd & 1) ? cosf(ang) : sinf(ang);
  } else if (blk == 56) {
    if (threadIdx.x < B) a.vals[threadIdx.x] = a.start_token[0];
  }
  grid_bar(bno);

  // ---- S2: part[l] = memory @ Wv_ca[l]^T + bv   (cross-attn V, T=1)
  if (blk < 128) {
    const int l = blk >> 5, tile = blk & 31;
    gemm64<0, 0>(sh, a.memory, D,
                 a.ca_in_w + (size_t)l * 3 * D * D + (size_t)2 * D * D, D,
                 a.ca_in_b + l * 3 * D + 2 * D,
                 a.part + (size_t)l * B * D, D,
                 (tile & 3) * 64, (tile >> 2) * 64, 0,
                 nullptr, nullptr, nullptr, 0,
                 nullptr, nullptr, nullptr, nullptr, nullptr);
  }
  grid_bar(bno);

  // ---- S3: ca_add[l] = part[l] @ Wo_ca[l]^T + bo
  if (blk < 128) {
    const int l = blk >> 5, tile = blk & 31;
    gemm64<0, 0>(sh, a.part + (size_t)l * B * D, D,
                 a.ca_out_w + (size_t)l * D * D, D, a.ca_out_b + l * D,
                 a.ca_add + (size_t)l * B * D, D,
                 (tile & 3) * 64, (tile >> 2) * 64, 0,
                 nullptr, nullptr, nullptr, 0,
                 nullptr, nullptr, nullptr, nullptr, nullptr);
  }
  grid_bar(bno);

  // ---- autoregressive decode --------------------------------------------
  for (int t = 0; t < P; t++) {
    for (int l = 0; l < L; l++) {
      float* kcp = a.kcache + (size_t)l * CS;
      float* vcp = a.vcache + (size_t)l * CS;

      // QKV projection (96 jobs); l==0 computes embedding inline and the
      // n0==0 blocks persist x for the residual path.
      if (blk < 96) {
        const int m0 = (blk & 3) * 64, n0 = (blk >> 2) * 64;
        if (l == 0)
          gemm64<1, 2>(sh, nullptr, 0, a.sa_in_w, D, a.sa_in_b, a.qkv, 3 * D,
                       m0, n0, 0, nullptr, kcp, vcp, t,
                       a.vals + (size_t)t * B, a.ve_W, a.ve_b, a.pe + t * D,
                       (n0 == 0) ? a.x : nullptr);
        else
          gemm64<0, 2>(sh, a.x, D, a.sa_in_w + (size_t)l * 3 * D * D, D,
                       a.sa_in_b + l * 3 * D, a.qkv, 3 * D, m0, n0, 0,
                       nullptr, kcp, vcp, t,
                       nullptr, nullptr, nullptr, nullptr, nullptr);
      }
      grid_bar(bno);

      // causal attention for position t: one wave per (b,h), 2048 units.
      {
        const int wid = threadIdx.x >> 6, lane = threadIdx.x & 63;
        const int u = blk * 8 + wid;
        const int b = u >> 3, h = u & 7;
        const float q = a.qkv[(size_t)b * 3 * D + h * HD + lane];
        const float* kb = kcp + (size_t)(b * H + h) * P * HD;
        const float* vb = vcp + (size_t)(b * H + h) * P * HD;
        float sc[P];
        const int nn = t + 1;
#pragma unroll
        for (int j = 0; j < P; j++)
          if (j < nn) {
            float p = q * kb[j * HD + lane];
#pragma unroll
            for (int o = 32; o; o >>= 1) p += __shfl_xor(p, o);
            sc[j] = p * 0.125f;   // 1/sqrt(64)
          }
        float mx = -1e30f;
#pragma unroll
        for (int j = 0; j < P; j++)
          if (j < nn) mx = fmaxf(mx, sc[j]);
        float s = 0.f;
#pragma unroll
        for (int j = 0; j < P; j++)
          if (j < nn) { sc[j] = expf(sc[j] - mx); s += sc[j]; }
        const float inv = 1.0f / s;
        float o = 0.f;
#pragma unroll
        for (int j = 0; j < P; j++)
          if (j < nn) o = fmaf(sc[j], vb[j * HD + lane], o);
        a.attn_o[(size_t)b * D + h * HD + lane] = o * inv;
      }
      grid_bar(bno);

      // output projection + residual:  U = x + attn_o @ Wo^T + bo  (32 jobs)
      if (blk < 32)
        gemm64<0, 4>(sh, a.attn_o, D, a.sa_out_w + (size_t)l * D * D, D,
                     a.sa_out_b + l * D, a.U, D,
                     (blk & 3) * 64, (blk >> 2) * 64, 0,
                     a.x, nullptr, nullptr, 0,
                     nullptr, nullptr, nullptr, nullptr, nullptr);
      grid_bar(bno);

      // x = LN2( LN1(U) + ca_add[l] )   — one block per row
      {
        const int b = blk, dd = threadIdx.x;
        const float u = a.U[(size_t)b * D + dd];
        const float m1 = rsum512(u, sbf) * (1.0f / D);
        const float d1 = u - m1;
        const float v1 = rsum512(d1 * d1, sbf) * (1.0f / D);
        const float z = d1 * rsqrtf(v1 + 1e-5f) * a.ln1_w[l * D + dd]
                        + a.ln1_b[l * D + dd];
        const float r2 = z + a.ca_add[(size_t)l * B * D + b * D + dd];
        const float m2 = rsum512(r2, sbf) * (1.0f / D);
        const float d2 = r2 - m2;
        const float v2 = rsum512(d2 * d2, sbf) * (1.0f / D);
        a.x[(size_t)b * D + dd] = d2 * rsqrtf(v2 + 1e-5f)
                                  * a.ln2_w[l * D + dd] + a.ln2_b[l * D + dd];
      }
      grid_bar(bno);

      // FFN1: hbuf = gelu(x @ W1^T + b1)   (128 jobs)
      if (blk < 128)
        gemm64<0, 1>(sh, a.x, D, a.lin1_w + (size_t)l * FF * D, D,
                     a.lin1_b + l * FF, a.hbuf, FF,
                     (blk & 3) * 64, (blk >> 2) * 64, 0,
                     nullptr, nullptr, nullptr, 0,
                     nullptr, nullptr, nullptr, nullptr, nullptr);
      grid_bar(bno);

      // FFN2 split-K: part[kc] = hbuf[:,kc*512:+512] @ W2[:,same]^T  (128 jobs)
      if (blk < 128) {
        const int kc4 = blk >> 5, tile = blk & 31;
        gemm64<0, 3>(sh, a.hbuf, FF, a.lin2_w + (size_t)l * D * FF, FF,
                     nullptr, a.part + (size_t)kc4 * B * D, D,
                     (tile & 3) * 64, (tile >> 2) * 64, kc4 * 512,
                     nullptr, nullptr, nullptr, 0,
                     nullptr, nullptr, nullptr, nullptr, nullptr);
      }
      grid_bar(bno);

      // x = LN3( x + sum(part) + b2 )
      {
        const int b = blk, dd = threadIdx.x;
        const size_t o = (size_t)b * D + dd;
        const float s0 = a.x[o] + a.part[o] + a.part[(size_t)B * D + o]
                       + a.part[(size_t)2 * B * D + o]
                       + a.part[(size_t)3 * B * D + o] + a.lin2_b[l * D + dd];
        const float m1 = rsum512(s0, sbf) * (1.0f / D);
        const float d1 = s0 - m1;
        const float v1 = rsum512(d1 * d1, sbf) * (1.0f / D);
        a.x[o] = d1 * rsqrtf(v1 + 1e-5f) * a.ln3_w[l * D + dd]
                 + a.ln3_b[l * D + dd];
      }
      grid_bar(bno);
    }

    // head stage 1: hh = gelu(x @ o1_w^T + o1_b)   (16 jobs)
    if (blk < 16)
      gemm64<0, 1>(sh, a.x, D, a.o1_w, D, a.o1_b, a.hh, 256,
                   (blk & 3) * 64, (blk >> 2) * 64, 0,
                   nullptr, nullptr, nullptr, 0,
                   nullptr, nullptr, nullptr, nullptr, nullptr);
    grid_bar(bno);

    // head stage 2: nv = hh @ o2_w^T + o2_b ; store out + vals[t+1]
    if (blk < 32) {
      const int wid = threadIdx.x >> 6, lane = threadIdx.x & 63;
      const int r = blk * 8 + wid;
      float p = 0.f;
#pragma unroll
      for (int i = 0; i < 4; i++)
        p = fmaf(a.hh[(size_t)r * 256 + lane + i * 64], a.o2_w[lane + i * 64], p);
#pragma unroll
      for (int o = 32; o; o >>= 1) p += __shfl_xor(p, o);
      if (lane == 0) {
        const float v = p + a.o2_b[0];
        a.vals[(size_t)(t + 1) * B + r] = v;
        a.out[(size_t)r * P + t] = v;
      }
    }
    grid_bar(bno);
  }

  if (blk == 0 && threadIdx.x == 0)
    __hip_atomic_store(&g_base, bno, __ATOMIC_RELAXED,
                       __HIP_MEMORY_SCOPE_AGENT);
}

// ---------------------------------------------------------------------------
extern "C" void kernel_launch(void* const* d_in, const int* in_sizes, int n_in,
                              void* d_out, int out_size, void* d_ws,
                              size_t ws_size, hipStream_t stream)
{
  (void)in_sizes; (void)n_in; (void)out_size; (void)ws_size;
  MegaArgs h;
  h.context     = (const float*)d_in[0];
  h.start_token = (const float*)d_in[1];
  h.ctx_W  = (const float*)d_in[2];
  h.ctx_b  = (const float*)d_in[3];
  h.ve_W   = (const float*)d_in[4];
  h.ve_b   = (const float*)d_in[5];
  h.sa_in_w  = (const float*)d_in[6];
  h.sa_in_b  = (const float*)d_in[7];
  h.sa_out_w = (const float*)d_in[8];
  h.sa_out_b = (const float*)d_in[9];
  h.ca_in_w  = (const float*)d_in[10];
  h.ca_in_b  = (const float*)d_in[11];
  h.ca_out_w = (const float*)d_in[12];
  h.ca_out_b = (const float*)d_in[13];
  h.lin1_w = (const float*)d_in[14];
  h.lin1_b = (const float*)d_in[15];
  h.lin2_w = (const float*)d_in[16];
  h.lin2_b = (const float*)d_in[17];
  h.ln1_w = (const float*)d_in[18];
  h.ln1_b = (const float*)d_in[19];
  h.ln2_w = (const float*)d_in[20];
  h.ln2_b = (const float*)d_in[21];
  h.ln3_w = (const float*)d_in[22];
  h.ln3_b = (const float*)d_in[23];
  h.o1_w = (const float*)d_in[24];
  h.o1_b = (const float*)d_in[25];
  h.o2_w = (const float*)d_in[26];
  h.o2_b = (const float*)d_in[27];
  h.out = (float*)d_out;

  float* ws = (float*)d_ws;
  size_t off = 0;
  h.pe      = ws + off; off += (size_t)P * D;
  h.vals    = ws + off; off += (size_t)(P + 1) * B;
  h.memory  = ws + off; off += (size_t)B * D;
  h.ca_add  = ws + off; off += (size_t)L * B * D;
  h.x       = ws + off; off += (size_t)B * D;
  h.qkv     = ws + off; off += (size_t)B * 3 * D;
  h.attn_o  = ws + off; off += (size_t)B * D;
  h.U       = ws + off; off += (size_t)B * D;
  h.hbuf    = ws + off; off += (size_t)B * FF;
  h.part    = ws + off; off += (size_t)4 * B * D;   // aliases setup vtmp
  h.hh      = ws + off; off += (size_t)B * 256;
  h.kcache  = ws + off; off += (size_t)L * CS;
  h.vcache  = ws + off; off += (size_t)L * CS;

  void* kargs[] = { &h };
  hipLaunchCooperativeKernel(mega, dim3(NBLK), dim3(NTHR), kargs, 0, stream);
}

// Round 4
// 12763.010 us; speedup vs baseline: 7.7348x; 1.8790x over previous
//
#include <hip/hip_runtime.h>
#include <math.h>

// ---------------------------------------------------------------------------
// TimeSeriesTransformerDecoder — cooperative mega-kernel, v3.
//  * KV-cached incremental decoding (exact under causal mask).
//  * Cross-attn T=1 -> softmax==1 -> per-layer constant ca_add.
//  * v3: FENCE-FREE sync. v2's __threadfence() = buffer_wbl2+inv per barrier
//    -> full per-XCD L2 flush x723 (3.86 GB HBM refetch, 30us/barrier).
//    Now: cross-block data uses relaxed AGENT-scope atomic ld/st (sc0 sc1,
//    coherent at L3, no flush); weights stay plain-cached (read-only, L2-hot);
//    barrier = two-level relaxed counter tree, zero fences.
// ---------------------------------------------------------------------------

#define B    256
#define D    512
#define H    8
#define HD   64
#define L    4
#define FF   2048
#define P    24
#define NBLK 256
#define NTHR 512
#define NGRP 8
#define GSZ  32
#define CS   ((size_t)B * H * P * HD)   // per-layer KV-cache stride

struct MegaArgs {
  const float *context, *start_token, *ctx_W, *ctx_b, *ve_W, *ve_b;
  const float *sa_in_w, *sa_in_b, *sa_out_w, *sa_out_b;
  const float *ca_in_w, *ca_in_b, *ca_out_w, *ca_out_b;
  const float *lin1_w, *lin1_b, *lin2_w, *lin2_b;
  const float *ln1_w, *ln1_b, *ln2_w, *ln2_b, *ln3_w, *ln3_b;
  const float *o1_w, *o1_b, *o2_w, *o2_b;
  float *out;
  float *pe, *vals, *memory, *ca_add, *x, *qbuf, *hbuf, *part, *hh,
        *kcache, *vcache;
};

// ---- coherent access helpers: relaxed agent atomics -> global_* sc0 sc1,
//      per-access coherent across XCDs, NO cache flush.
__device__ __forceinline__ float gld(const float* p)
{
  return __hip_atomic_load((float*)p, __ATOMIC_RELAXED,
                           __HIP_MEMORY_SCOPE_AGENT);
}
__device__ __forceinline__ void gst(float* p, float v)
{
  __hip_atomic_store(p, v, __ATOMIC_RELAXED, __HIP_MEMORY_SCOPE_AGENT);
}

// ---- barrier state: monotonic across graph replays, no resets.
__device__ __align__(128) unsigned g_cnt[NGRP * 32];  // 8 counters, 128B apart
__device__ __align__(128) unsigned g_root = 0;
__device__ __align__(128) unsigned g_gen  = 0;
__device__ __align__(128) unsigned g_base = 0;

__device__ __forceinline__ void grid_bar(unsigned &bno)
{
  ++bno;
  __syncthreads();  // emits s_waitcnt vmcnt(0): all sc1 stores at coherence pt
  if (threadIdx.x == 0) {
    unsigned* cnt = &g_cnt[(blockIdx.x & (NGRP - 1)) * 32];
    const unsigned o = __hip_atomic_fetch_add(cnt, 1u, __ATOMIC_RELAXED,
                                              __HIP_MEMORY_SCOPE_AGENT);
    if (o == bno * GSZ - 1u) {                 // last arriver of this group
      const unsigned r = __hip_atomic_fetch_add(&g_root, 1u, __ATOMIC_RELAXED,
                                                __HIP_MEMORY_SCOPE_AGENT);
      if (r == bno * NGRP - 1u)
        __hip_atomic_store(&g_gen, bno, __ATOMIC_RELAXED,
                           __HIP_MEMORY_SCOPE_AGENT);
    }
    while (__hip_atomic_load(&g_gen, __ATOMIC_RELAXED,
                             __HIP_MEMORY_SCOPE_AGENT) < bno)
      __builtin_amdgcn_s_sleep(4);
  }
  __syncthreads();
}

__device__ __forceinline__ float gelu_f(float v)
{
  return 0.5f * v * (1.0f + erff(v * 0.70710678118654752f));
}

// ---------------------------------------------------------------------------
// 64x64 tile GEMM over K chunk [k0, k0+KL). 512 threads, 2x4 micro-tile,
// register-prefetch software pipeline. A via coherent gld; W plain-cached.
// LOADER: 0 = gld(A); 1 = embedding on the fly; 2 = (unused)
// EPI: 0 = +bias -> gst C ; 1 = +bias+gelu -> gst C ;
//      2 = +bias, n<D -> qbuf, else -> kv caches ; 3 = raw partial -> gst C
// ---------------------------------------------------------------------------
template <int LOADER, int EPI>
__device__ void gemmK(float* sh,
                      const float* A, int lda,
                      const float* W, int ldw, const float* bias,
                      float* C, int ldc, int m0, int n0, int k0, int KL,
                      float* kcp, float* vcp, int t,
                      const float* valst, const float* veW, const float* veb,
                      const float* pet, float* xout)
{
  float* As = sh;             // [16][68]
  float* Ws = sh + 16 * 68;
  const int tid = threadIdx.x;
  const int c  = tid & 15;    // k within chunk
  const int r  = tid >> 4;    // 0..31 -> rows r, r+32
  const int tm = tid >> 4;    // micro rows tm*2, tm*2+1
  const int tn = tid & 15;    // micro cols tn*4..+3

  float vv0 = 0.f, vv1 = 0.f;
  if constexpr (LOADER == 1) {
    vv0 = gld(valst + m0 + r);
    vv1 = gld(valst + m0 + r + 32);
  }

  auto ldA = [&](int kb, int rr, float vv) -> float {
    const int k = k0 + kb + c;
    if constexpr (LOADER == 1) {
      const float av = vv * veW[k] + veb[k] + gld(pet + k);
      if (xout) gst(xout + (size_t)(m0 + rr) * D + k, av);
      return av;
    } else {
      return gld(A + (size_t)(m0 + rr) * lda + k);
    }
  };
  auto ldW = [&](int kb, int rr) -> float {
    return W[(size_t)(n0 + rr) * ldw + k0 + kb + c];
  };

  float a0 = ldA(0, r, vv0), a1 = ldA(0, r + 32, vv1);
  float w0 = ldW(0, r),      w1 = ldW(0, r + 32);
  float acc[2][4] = {};

  for (int kb = 0; kb < KL; kb += 16) {
    As[c * 68 + r]      = a0;
    As[c * 68 + r + 32] = a1;
    Ws[c * 68 + r]      = w0;
    Ws[c * 68 + r + 32] = w1;
    __syncthreads();
    if (kb + 16 < KL) {                       // prefetch next chunk into regs
      a0 = ldA(kb + 16, r, vv0); a1 = ldA(kb + 16, r + 32, vv1);
      w0 = ldW(kb + 16, r);      w1 = ldW(kb + 16, r + 32);
    }
#pragma unroll
    for (int kk = 0; kk < 16; kk++) {
      const float2 a2 = *(const float2*)(As + kk * 68 + tm * 2);
      const float4 w4 = *(const float4*)(Ws + kk * 68 + tn * 4);
      acc[0][0] = fmaf(a2.x, w4.x, acc[0][0]);
      acc[0][1] = fmaf(a2.x, w4.y, acc[0][1]);
      acc[0][2] = fmaf(a2.x, w4.z, acc[0][2]);
      acc[0][3] = fmaf(a2.x, w4.w, acc[0][3]);
      acc[1][0] = fmaf(a2.y, w4.x, acc[1][0]);
      acc[1][1] = fmaf(a2.y, w4.y, acc[1][1]);
      acc[1][2] = fmaf(a2.y, w4.z, acc[1][2]);
      acc[1][3] = fmaf(a2.y, w4.w, acc[1][3]);
    }
    __syncthreads();
  }

#pragma unroll
  for (int i = 0; i < 2; i++) {
    const int m = m0 + tm * 2 + i;
#pragma unroll
    for (int j = 0; j < 4; j++) {
      const int n = n0 + tn * 4 + j;
      float v = acc[i][j];
      if constexpr (EPI != 3) v += bias[n];
      if constexpr (EPI == 1) v = gelu_f(v);
      if constexpr (EPI == 2) {
        if (n < D) {
          gst(C + (size_t)m * D + n, v);                       // q -> qbuf
        } else if (n < 2 * D) {
          const int f = n - D;
          gst(kcp + ((size_t)(m * H + (f >> 6)) * P + t) * HD + (f & 63), v);
        } else {
          const int f = n - 2 * D;
          gst(vcp + ((size_t)(m * H + (f >> 6)) * P + t) * HD + (f & 63), v);
        }
      } else {
        gst(C + (size_t)m * ldc + n, v);
      }
    }
  }
}

// block-wide sum over 512 threads (8 waves)
__device__ __forceinline__ float rsum512(float v, float* sbf)
{
#pragma unroll
  for (int o = 32; o; o >>= 1) v += __shfl_xor(v, o);
  const int wid = threadIdx.x >> 6;
  if ((threadIdx.x & 63) == 0) sbf[wid] = v;
  __syncthreads();
  float s = 0.f;
#pragma unroll
  for (int w = 0; w < 8; w++) s += sbf[w];
  __syncthreads();
  return s;
}

__global__ __launch_bounds__(NTHR) void mega(MegaArgs a)
{
  __shared__ float sh[2 * 16 * 68];
  __shared__ float sbf[8];
  const int blk = blockIdx.x;
  unsigned bno = __hip_atomic_load(&g_base, __ATOMIC_RELAXED,
                                   __HIP_MEMORY_SCOPE_AGENT);
  float* attn_o = a.part + (size_t)4 * B * D;   // alias: part[4] slot

  // ---- S1: memory = context @ ctx_W^T + b (32 jobs) | pe table | vals init
  if (blk < 32) {
    gemmK<0, 0>(sh, a.context, D, a.ctx_W, D, a.ctx_b, a.memory, D,
                (blk & 3) * 64, (blk >> 2) * 64, 0, 512,
                nullptr, nullptr, 0, nullptr, nullptr, nullptr, nullptr,
                nullptr);
  } else if (blk < 56) {
    const int tt = blk - 32;
    const int dd = threadIdx.x;
    const float fr = expf((float)(dd & ~1) * (-9.210340371976184f / (float)D));
    const float ang = (float)tt * fr;
    gst(a.pe + tt * D + dd, (dd & 1) ? cosf(ang) : sinf(ang));
  } else if (blk == 56) {
    if (threadIdx.x < B) gst(a.vals + threadIdx.x, a.start_token[0]);
  }
  grid_bar(bno);

  // ---- S2: part[l] = memory @ Wv_ca[l]^T + bv   (cross-attn V, T=1)
  if (blk < 128) {
    const int l = blk >> 5, tile = blk & 31;
    gemmK<0, 0>(sh, a.memory, D,
                a.ca_in_w + (size_t)l * 3 * D * D + (size_t)2 * D * D, D,
                a.ca_in_b + l * 3 * D + 2 * D,
                a.part + (size_t)l * B * D, D,
                (tile & 3) * 64, (tile >> 2) * 64, 0, 512,
                nullptr, nullptr, 0, nullptr, nullptr, nullptr, nullptr,
                nullptr);
  }
  grid_bar(bno);

  // ---- S3: ca_add[l] = part[l] @ Wo_ca[l]^T + bo
  if (blk < 128) {
    const int l = blk >> 5, tile = blk & 31;
    gemmK<0, 0>(sh, a.part + (size_t)l * B * D, D,
                a.ca_out_w + (size_t)l * D * D, D, a.ca_out_b + l * D,
                a.ca_add + (size_t)l * B * D, D,
                (tile & 3) * 64, (tile >> 2) * 64, 0, 512,
                nullptr, nullptr, 0, nullptr, nullptr, nullptr, nullptr,
                nullptr);
  }
  grid_bar(bno);

  // ---- autoregressive decode --------------------------------------------
  for (int t = 0; t < P; t++) {
    for (int l = 0; l < L; l++) {
      float* kcp = a.kcache + (size_t)l * CS;
      float* vcp = a.vcache + (size_t)l * CS;

      // QKV projection (96 jobs); l==0 computes embedding inline; the
      // n0==0 blocks persist x for the residual path.
      if (blk < 96) {
        const int m0 = (blk & 3) * 64, n0 = (blk >> 2) * 64;
        if (l == 0)
          gemmK<1, 2>(sh, nullptr, 0, a.sa_in_w, D, a.sa_in_b, a.qbuf, D,
                      m0, n0, 0, 512, kcp, vcp, t,
                      a.vals + (size_t)t * B, a.ve_W, a.ve_b, a.pe + t * D,
                      (n0 == 0) ? a.x : nullptr);
        else
          gemmK<0, 2>(sh, a.x, D, a.sa_in_w + (size_t)l * 3 * D * D, D,
                      a.sa_in_b + l * 3 * D, a.qbuf, D, m0, n0, 0, 512,
                      kcp, vcp, t, nullptr, nullptr, nullptr, nullptr,
                      nullptr);
      }
      grid_bar(bno);

      // causal attention for position t: one wave per (b,h), 2048 units.
      {
        const int wid = threadIdx.x >> 6, lane = threadIdx.x & 63;
        const int u = blk * 8 + wid;
        const int b = u >> 3, h = u & 7;
        const float q = gld(a.qbuf + (size_t)b * D + h * HD + lane);
        const float* kb = kcp + (size_t)(b * H + h) * P * HD;
        const float* vb = vcp + (size_t)(b * H + h) * P * HD;
        float sc[P];
        const int nn = t + 1;
#pragma unroll
        for (int j = 0; j < P; j++)
          if (j < nn) {
            float p = q * gld(kb + j * HD + lane);
#pragma unroll
            for (int o = 32; o; o >>= 1) p += __shfl_xor(p, o);
            sc[j] = p * 0.125f;   // 1/sqrt(64)
          }
        float mx = -1e30f;
#pragma unroll
        for (int j = 0; j < P; j++)
          if (j < nn) mx = fmaxf(mx, sc[j]);
        float s = 0.f;
#pragma unroll
        for (int j = 0; j < P; j++)
          if (j < nn) { sc[j] = expf(sc[j] - mx); s += sc[j]; }
        const float inv = 1.0f / s;
        float o = 0.f;
#pragma unroll
        for (int j = 0; j < P; j++)
          if (j < nn) o = fmaf(sc[j], gld(vb + j * HD + lane), o);
        gst(attn_o + (size_t)b * D + h * HD + lane, o * inv);
      }
      grid_bar(bno);

      // out-proj split-K4: part[kc] = attn_o[:,kc*128:+128] @ Wo[:,..]^T
      if (blk < 128) {
        const int kc = blk >> 5, tile = blk & 31;
        gemmK<0, 3>(sh, attn_o, D, a.sa_out_w + (size_t)l * D * D, D,
                    nullptr, a.part + (size_t)kc * B * D, D,
                    (tile & 3) * 64, (tile >> 2) * 64, kc * 128, 128,
                    nullptr, nullptr, 0, nullptr, nullptr, nullptr, nullptr,
                    nullptr);
      }
      grid_bar(bno);

      // x = LN2( LN1(x + sum4(part) + bo) + ca_add[l] )  — one block/row
      {
        const int b = blk, dd = threadIdx.x;
        const size_t o = (size_t)b * D + dd;
        float u = gld(a.x + o) + a.sa_out_b[l * D + dd];
#pragma unroll
        for (int kc = 0; kc < 4; kc++)
          u += gld(a.part + (size_t)kc * B * D + o);
        const float m1 = rsum512(u, sbf) * (1.0f / D);
        const float d1 = u - m1;
        const float v1 = rsum512(d1 * d1, sbf) * (1.0f / D);
        const float z = d1 * rsqrtf(v1 + 1e-5f) * a.ln1_w[l * D + dd]
                        + a.ln1_b[l * D + dd];
        const float r2 = z + gld(a.ca_add + (size_t)l * B * D + o);
        const float m2 = rsum512(r2, sbf) * (1.0f / D);
        const float d2 = r2 - m2;
        const float v2 = rsum512(d2 * d2, sbf) * (1.0f / D);
        gst(a.x + o, d2 * rsqrtf(v2 + 1e-5f) * a.ln2_w[l * D + dd]
                     + a.ln2_b[l * D + dd]);
      }
      grid_bar(bno);

      // FFN1: hbuf = gelu(x @ W1^T + b1)   (128 jobs)
      if (blk < 128)
        gemmK<0, 1>(sh, a.x, D, a.lin1_w + (size_t)l * FF * D, D,
                    a.lin1_b + l * FF, a.hbuf, FF,
                    (blk & 3) * 64, (blk >> 2) * 64, 0, 512,
                    nullptr, nullptr, 0, nullptr, nullptr, nullptr, nullptr,
                    nullptr);
      grid_bar(bno);

      // FFN2 split-K8: part[kc] = hbuf[:,kc*256:+256] @ W2[:,..]^T (256 jobs)
      {
        const int kc = blk >> 5, tile = blk & 31;
        gemmK<0, 3>(sh, a.hbuf, FF, a.lin2_w + (size_t)l * D * FF, FF,
                    nullptr, a.part + (size_t)kc * B * D, D,
                    (tile & 3) * 64, (tile >> 2) * 64, kc * 256, 256,
                    nullptr, nullptr, 0, nullptr, nullptr, nullptr, nullptr,
                    nullptr);
      }
      grid_bar(bno);

      // x = LN3( x + sum8(part) + b2 )
      {
        const int b = blk, dd = threadIdx.x;
        const size_t o = (size_t)b * D + dd;
        float s0 = gld(a.x + o) + a.lin2_b[l * D + dd];
#pragma unroll
        for (int kc = 0; kc < 8; kc++)
          s0 += gld(a.part + (size_t)kc * B * D + o);
        const float m1 = rsum512(s0, sbf) * (1.0f / D);
        const float d1 = s0 - m1;
        const float v1 = rsum512(d1 * d1, sbf) * (1.0f / D);
        gst(a.x + o, d1 * rsqrtf(v1 + 1e-5f) * a.ln3_w[l * D + dd]
                     + a.ln3_b[l * D + dd]);
      }
      grid_bar(bno);
    }

    // head stage 1: hh = gelu(x @ o1_w^T + o1_b)   (16 jobs)
    if (blk < 16)
      gemmK<0, 1>(sh, a.x, D, a.o1_w, D, a.o1_b, a.hh, 256,
                  (blk & 3) * 64, (blk >> 2) * 64, 0, 512,
                  nullptr, nullptr, 0, nullptr, nullptr, nullptr, nullptr,
                  nullptr);
    grid_bar(bno);

    // head stage 2: nv = hh @ o2_w^T + o2_b ; store out + vals[t+1]
    if (blk < 32) {
      const int wid = threadIdx.x >> 6, lane = threadIdx.x & 63;
      const int r = blk * 8 + wid;
      float p = 0.f;
#pragma unroll
      for (int i = 0; i < 4; i++)
        p = fmaf(gld(a.hh + (size_t)r * 256 + lane + i * 64),
                 a.o2_w[lane + i * 64], p);
#pragma unroll
      for (int o = 32; o; o >>= 1) p += __shfl_xor(p, o);
      if (lane == 0) {
        const float v = p + a.o2_b[0];
        gst(a.vals + (size_t)(t + 1) * B + r, v);
        a.out[(size_t)r * P + t] = v;
      }
    }
    grid_bar(bno);
  }

  if (blk == 0 && threadIdx.x == 0)
    __hip_atomic_store(&g_base, bno, __ATOMIC_RELAXED,
                       __HIP_MEMORY_SCOPE_AGENT);
}

// ---------------------------------------------------------------------------
extern "C" void kernel_launch(void* const* d_in, const int* in_sizes, int n_in,
                              void* d_out, int out_size, void* d_ws,
                              size_t ws_size, hipStream_t stream)
{
  (void)in_sizes; (void)n_in; (void)out_size; (void)ws_size;
  MegaArgs h;
  h.context     = (const float*)d_in[0];
  h.start_token = (const float*)d_in[1];
  h.ctx_W  = (const float*)d_in[2];
  h.ctx_b  = (const float*)d_in[3];
  h.ve_W   = (const float*)d_in[4];
  h.ve_b   = (const float*)d_in[5];
  h.sa_in_w  = (const float*)d_in[6];
  h.sa_in_b  = (const float*)d_in[7];
  h.sa_out_w = (const float*)d_in[8];
  h.sa_out_b = (const float*)d_in[9];
  h.ca_in_w  = (const float*)d_in[10];
  h.ca_in_b  = (const float*)d_in[11];
  h.ca_out_w = (const float*)d_in[12];
  h.ca_out_b = (const float*)d_in[13];
  h.lin1_w = (const float*)d_in[14];
  h.lin1_b = (const float*)d_in[15];
  h.lin2_w = (const float*)d_in[16];
  h.lin2_b = (const float*)d_in[17];
  h.ln1_w = (const float*)d_in[18];
  h.ln1_b = (const float*)d_in[19];
  h.ln2_w = (const float*)d_in[20];
  h.ln2_b = (const float*)d_in[21];
  h.ln3_w = (const float*)d_in[22];
  h.ln3_b = (const float*)d_in[23];
  h.o1_w = (const float*)d_in[24];
  h.o1_b = (const float*)d_in[25];
  h.o2_w = (const float*)d_in[26];
  h.o2_b = (const float*)d_in[27];
  h.out = (float*)d_out;

  float* ws = (float*)d_ws;
  size_t off = 0;
  h.pe      = ws + off; off += (size_t)P * D;
  h.vals    = ws + off; off += (size_t)(P + 1) * B;
  h.memory  = ws + off; off += (size_t)B * D;
  h.ca_add  = ws + off; off += (size_t)L * B * D;
  h.x       = ws + off; off += (size_t)B * D;
  h.qbuf    = ws + off; off += (size_t)B * D;
  h.hbuf    = ws + off; off += (size_t)B * FF;
  h.part    = ws + off; off += (size_t)8 * B * D;  // [8][B][D]; part[4]=attn_o
  h.hh      = ws + off; off += (size_t)B * 256;
  h.kcache  = ws + off; off += (size_t)L * CS;
  h.vcache  = ws + off; off += (size_t)L * CS;

  void* kargs[] = { &h };
  hipLaunchCooperativeKernel(mega, dim3(NBLK), dim3(NTHR), kargs, 0, stream);
}